// Round 1
// baseline (359.889 us; speedup 1.0000x reference)
//
#include <hip/hip_runtime.h>
#include <hip/hip_bf16.h>

#define DEVI static __device__ __forceinline__

typedef __attribute__((ext_vector_type(8))) short short8;
typedef __attribute__((ext_vector_type(4))) float f32x4;

#define B_   8
#define O_   100
#define N_   4096
#define TOKD 2048
#define D_   256
#define K_   128
#define H_   8
#define M_   (B_*N_)   // 32768

DEVI unsigned short f2bf(float f) {
    unsigned u = __float_as_uint(f);
    u = (u + 0x7FFFu + ((u >> 16) & 1u)) >> 16;   // RNE
    return (unsigned short)u;
}
DEVI float bf2f(unsigned v) { return __uint_as_float(v << 16); }

// ---------- W_tok -> bf16, transposed to [n=256][k=2048] ----------
__global__ __launch_bounds__(256) void k_wtokprep(const float* __restrict__ W,
                                                  unsigned short* __restrict__ wtb) {
    int idx = blockIdx.x * 256 + threadIdx.x;   // 524288 total, coalesced read
    int k = idx >> 8;
    int n = idx & 255;
    wtb[n * TOKD + k] = f2bf(W[idx]);
}

// ---------- GEMM1: tp_raw[M,256] = tokens[M,2048] @ W_tok  (bf16 MFMA) ----------
__global__ __launch_bounds__(512) void k_gemm1(const float* __restrict__ A,
                                               const unsigned short* __restrict__ Bt,
                                               float* __restrict__ C) {
    __shared__ uint4 AsU[640];    // 128 rows * 80B (32 bf16 + 16B pad -> conflict-free)
    __shared__ uint4 BsU[1280];   // 256 rows * 80B
    char* As = (char*)AsU;
    char* Bs = (char*)BsU;
    const int t = threadIdx.x;
    const int bm = blockIdx.x;
    const int lane = t & 63, w = t >> 6;
    const int wm = w >> 2, wn = w & 3;       // wave tile 64x64 in 128x256 block tile
    const int lr = lane >> 4, lc = lane & 15;

    const int ar = t >> 2, ako = (t & 3) * 8;     // A staging: 8 f32/thread
    const int bn = t >> 1, bko = (t & 1) * 16;    // B staging: 16 bf16/thread
    const float* aptr = A + (size_t)(bm * 128 + ar) * TOKD + ako;
    const unsigned short* bptr = Bt + (size_t)bn * TOKD + bko;

    float4 a0 = *(const float4*)(aptr);
    float4 a1 = *(const float4*)(aptr + 4);
    uint4  b0 = *(const uint4*)(bptr);
    uint4  b1 = *(const uint4*)(bptr + 8);

    f32x4 acc[4][4] = {};
    char* aw = As + ar * 80 + ako * 2;
    char* bw = Bs + bn * 80 + bko * 2;
    const char* arow = As + (wm * 64 + lc) * 80 + lr * 16;
    const char* brow = Bs + (wn * 64 + lc) * 80 + lr * 16;

    for (int kt = 0; kt < TOKD / 32; ++kt) {
        uint4 av;
        av.x = f2bf(a0.x) | ((unsigned)f2bf(a0.y) << 16);
        av.y = f2bf(a0.z) | ((unsigned)f2bf(a0.w) << 16);
        av.z = f2bf(a1.x) | ((unsigned)f2bf(a1.y) << 16);
        av.w = f2bf(a1.z) | ((unsigned)f2bf(a1.w) << 16);
        *(uint4*)aw = av;
        *(uint4*)bw = b0;
        *(uint4*)(bw + 16) = b1;
        if (kt < TOKD / 32 - 1) {   // prefetch next K-step into regs (overlaps MFMA)
            const float* ap = aptr + (kt + 1) * 32;
            a0 = *(const float4*)(ap);
            a1 = *(const float4*)(ap + 4);
            const unsigned short* bp = bptr + (kt + 1) * 32;
            b0 = *(const uint4*)(bp);
            b1 = *(const uint4*)(bp + 8);
        }
        __syncthreads();
        short8 af[4], bfv[4];
        #pragma unroll
        for (int mi = 0; mi < 4; ++mi) af[mi] = *(const short8*)(arow + mi * 16 * 80);
        #pragma unroll
        for (int ni = 0; ni < 4; ++ni) bfv[ni] = *(const short8*)(brow + ni * 16 * 80);
        #pragma unroll
        for (int mi = 0; mi < 4; ++mi)
            #pragma unroll
            for (int ni = 0; ni < 4; ++ni)
                acc[mi][ni] = __builtin_amdgcn_mfma_f32_16x16x32_bf16(af[mi], bfv[ni], acc[mi][ni], 0, 0, 0);
        __syncthreads();
    }
    const int rb = bm * 128 + wm * 64 + lr * 4;
    const int cb = wn * 64 + lc;
    #pragma unroll
    for (int mi = 0; mi < 4; ++mi)
        #pragma unroll
        for (int ni = 0; ni < 4; ++ni)
            #pragma unroll
            for (int r = 0; r < 4; ++r)
                C[(size_t)(rb + mi * 16 + r) * D_ + cb + ni * 16] = acc[mi][ni][r];
}

// ---------- LN over rows of tp_raw (+b_tok), store bf16 ----------
__global__ __launch_bounds__(256) void k_ln1(const float* __restrict__ raw, const float* __restrict__ bt0,
                                             const float* __restrict__ g, const float* __restrict__ bt,
                                             unsigned short* __restrict__ tp) {
    const int lane = threadIdx.x & 63, wid = threadIdx.x >> 6;
    const int row = blockIdx.x * 4 + wid;
    const int c0 = lane * 4;
    float4 x = *(const float4*)(raw + (size_t)row * D_ + c0);
    float4 b4 = *(const float4*)(bt0 + c0);
    float x0 = x.x + b4.x, x1 = x.y + b4.y, x2 = x.z + b4.z, x3 = x.w + b4.w;
    float s = x0 + x1 + x2 + x3;
    float q = x0*x0 + x1*x1 + x2*x2 + x3*x3;
    #pragma unroll
    for (int m = 1; m < 64; m <<= 1) { s += __shfl_xor(s, m); q += __shfl_xor(q, m); }
    float mean = s * (1.f/256.f);
    float var = q * (1.f/256.f) - mean*mean;
    float rs = rsqrtf(var + 1e-5f);
    float4 g4 = *(const float4*)(g + c0);
    float4 t4 = *(const float4*)(bt + c0);
    ushort4 o;
    o.x = f2bf((x0-mean)*rs*g4.x + t4.x);
    o.y = f2bf((x1-mean)*rs*g4.y + t4.y);
    o.z = f2bf((x2-mean)*rs*g4.z + t4.z);
    o.w = f2bf((x3-mean)*rs*g4.w + t4.w);
    *(ushort4*)(tp + (size_t)row * D_ + c0) = o;
}

// ---------- top-128 per (b,o) row (exact jax tie-break) + row sum ----------
__global__ __launch_bounds__(256) void k_topk(const float* __restrict__ act,
                                              int* __restrict__ oidx,
                                              float* __restrict__ asum) {
    __shared__ float redf[4];
    __shared__ int redi[4];
    __shared__ int cnts[2];
    __shared__ int eql[4096];
    const int t = threadIdx.x, lane = t & 63, wid = t >> 6;
    const int blk = blockIdx.x;
    const float* rp = act + (size_t)blk * N_;
    unsigned v[16];
    float fs = 0.f;
    #pragma unroll
    for (int i = 0; i < 16; ++i) {
        float f = rp[t + i * 256];
        v[i] = __float_as_uint(f);   // non-negative floats: bits are order-preserving
        fs += f;
    }
    if (t == 0) { cnts[0] = 0; cnts[1] = 0; }
    #pragma unroll
    for (int m = 1; m < 64; m <<= 1) fs += __shfl_xor(fs, m);
    if (!lane) redf[wid] = fs;
    __syncthreads();
    if (t == 0) asum[blk] = fmaxf(redf[0] + redf[1] + redf[2] + redf[3], 1e-8f);

    // max thr with count(bits >= thr) >= 128
    unsigned thr = 0u;
    for (int bit = 31; bit >= 0; --bit) {
        unsigned cand = thr | (1u << bit);
        int c = 0;
        #pragma unroll
        for (int i = 0; i < 16; ++i) c += (v[i] >= cand) ? 1 : 0;
        #pragma unroll
        for (int m = 1; m < 64; m <<= 1) c += __shfl_xor(c, m);
        __syncthreads();
        if (!lane) redi[wid] = c;
        __syncthreads();
        int tot = redi[0] + redi[1] + redi[2] + redi[3];
        if (tot >= K_) thr = cand;
    }
    #pragma unroll
    for (int i = 0; i < 16; ++i) {
        unsigned x = v[i];
        if (x > thr) {
            int p = atomicAdd(&cnts[0], 1);
            oidx[blk * K_ + p] = t + i * 256;     // set semantics: order irrelevant downstream
        } else if (x == thr) {
            int p = atomicAdd(&cnts[1], 1);
            eql[p] = t + i * 256;
        }
    }
    __syncthreads();
    const int g = cnts[0], E = cnts[1], m = K_ - g;   // ties: lowest index first (jax)
    int last = -1;
    for (int slot = 0; slot < m; ++slot) {
        int best = 0x7FFFFFFF;
        for (int i = t; i < E; i += 256) {
            int e = eql[i];
            if (e > last && e < best) best = e;
        }
        #pragma unroll
        for (int mm = 1; mm < 64; mm <<= 1) best = min(best, __shfl_xor(best, mm));
        __syncthreads();
        if (!lane) redi[wid] = best;
        __syncthreads();
        best = min(min(redi[0], redi[1]), min(redi[2], redi[3]));
        if (t == 0) oidx[blk * K_ + g + slot] = best;
        last = best;
    }
}

// ---------- weighted-average branch (unnormalized; /asum in k_attn) ----------
__global__ __launch_bounds__(256) void k_wavg(const float* __restrict__ act,
                                              const unsigned short* __restrict__ tp,
                                              float* __restrict__ wavg) {
    const int kc = blockIdx.x;   // 32 K-chunks of 128 n
    const int b = blockIdx.y;    // 8
    const int d = threadIdx.x;
    const unsigned short* tpb = tp + ((size_t)b * N_ + kc * 128) * D_ + d;
    const float* actb = act + (size_t)b * O_ * N_ + kc * 128;
    for (int oc = 0; oc < 10; ++oc) {
        float acc[10] = {};
        for (int q = 0; q < 32; ++q) {
            float t0 = bf2f(tpb[(q * 4 + 0) * D_]);
            float t1 = bf2f(tpb[(q * 4 + 1) * D_]);
            float t2 = bf2f(tpb[(q * 4 + 2) * D_]);
            float t3 = bf2f(tpb[(q * 4 + 3) * D_]);
            #pragma unroll
            for (int oj = 0; oj < 10; ++oj) {   // act addr wave-uniform -> s_load
                float4 a4 = *(const float4*)(actb + (size_t)(oc * 10 + oj) * N_ + q * 4);
                acc[oj] += a4.x * t0 + a4.y * t1 + a4.z * t2 + a4.w * t3;
            }
        }
        #pragma unroll
        for (int oj = 0; oj < 10; ++oj)
            atomicAdd(&wavg[((size_t)b * O_ + oc * 10 + oj) * D_ + d], acc[oj]);
    }
}

// ---------- fold Wq/Wk through the shared query: qW[h,e], qb[h] ----------
__global__ __launch_bounds__(256) void k_qwprep(const float* __restrict__ pq,
    const float* __restrict__ Wq, const float* __restrict__ bq,
    const float* __restrict__ Wk, const float* __restrict__ bk,
    float* __restrict__ qW, float* __restrict__ qb) {
    __shared__ float qh[D_];
    const int t = threadIdx.x;
    float s = bq[t];
    for (int e = 0; e < D_; ++e) s += pq[e] * Wq[e * D_ + t];
    qh[t] = s;
    __syncthreads();
    #pragma unroll
    for (int h = 0; h < 8; ++h) {
        float u = 0.f;
        #pragma unroll
        for (int dd = 0; dd < 32; ++dd) u += qh[h * 32 + dd] * Wk[t * D_ + h * 32 + dd];
        qW[h * D_ + t] = u;
    }
    if (t < 8) {
        float u = 0.f;
        for (int dd = 0; dd < 32; ++dd) u += qh[t * 32 + dd] * bk[t * 32 + dd];
        qb[t] = u;
    }
}

// ---------- gather + attention + Wo + LN + combine + final LN ----------
__global__ __launch_bounds__(256) void k_attn(
    const unsigned short* __restrict__ tp, const int* __restrict__ oidx,
    const float* __restrict__ qW, const float* __restrict__ qb,
    const float* __restrict__ Wv, const float* __restrict__ bv,
    const float* __restrict__ Wo, const float* __restrict__ bo,
    const float* __restrict__ g_pn, const float* __restrict__ bt_pn,
    const float* __restrict__ g_on, const float* __restrict__ bt_on,
    const float* __restrict__ wavg, const float* __restrict__ asum,
    float* __restrict__ outp)
{
    __shared__ uint4 tgU[4096];      // 128 rows x 512B, XOR-swizzled
    __shared__ float sc[H_ * K_];
    __shared__ float ul[H_ * D_];
    __shared__ float pool_lds[D_];
    __shared__ float redf[8];
    __shared__ int idxl[K_];
    char* tg = (char*)tgU;

    const int t = threadIdx.x, lane = t & 63, wid = t >> 6;
    const int blk = blockIdx.x;
    const int b = blk / O_;

    if (t < K_) idxl[t] = oidx[blk * K_ + t];
    __syncthreads();

    #pragma unroll
    for (int it = 0; it < 16; ++it) {      // gather top-128 token rows (bf16)
        int c = t + it * 256;
        int j = c >> 5, ch = c & 31;
        uint4 v = *(const uint4*)(tp + ((size_t)(b * N_ + idxl[j])) * D_ + ch * 8);
        *(uint4*)(tg + ((j * 512 + ch * 16) ^ ((j & 7) << 4))) = v;
    }
    __syncthreads();

    #pragma unroll
    for (int kk = 0; kk < 4; ++kk) {       // scores[h][j] = t.qW + qb, /sqrt(32)
        int oid = t + kk * 256;
        int h = oid >> 7, j = oid & 127;
        const float* qr = qW + h * D_;
        float s = 0.f;
        #pragma unroll 4
        for (int e8 = 0; e8 < 32; ++e8) {
            uint4 tv = *(const uint4*)(tg + ((j * 512 + e8 * 16) ^ ((j & 7) << 4)));
            const float* qe = qr + e8 * 8;
            s += bf2f(tv.x & 0xffffu) * qe[0] + bf2f(tv.x >> 16) * qe[1]
               + bf2f(tv.y & 0xffffu) * qe[2] + bf2f(tv.y >> 16) * qe[3]
               + bf2f(tv.z & 0xffffu) * qe[4] + bf2f(tv.z >> 16) * qe[5]
               + bf2f(tv.w & 0xffffu) * qe[6] + bf2f(tv.w >> 16) * qe[7];
        }
        sc[h * K_ + j] = (s + qb[h]) * 0.1767766952966369f;
    }
    __syncthreads();

    #pragma unroll
    for (int hh = 0; hh < 2; ++hh) {       // softmax per head (wave handles 2 heads)
        int h = wid * 2 + hh;
        float v0 = sc[h * K_ + lane], v1 = sc[h * K_ + 64 + lane];
        float mx = fmaxf(v0, v1);
        #pragma unroll
        for (int m = 1; m < 64; m <<= 1) mx = fmaxf(mx, __shfl_xor(mx, m));
        float e0 = __expf(v0 - mx), e1 = __expf(v1 - mx);
        float ss = e0 + e1;
        #pragma unroll
        for (int m = 1; m < 64; m <<= 1) ss += __shfl_xor(ss, m);
        float inv = 1.0f / ss;
        sc[h * K_ + lane] = e0 * inv;
        sc[h * K_ + 64 + lane] = e1 * inv;
    }
    __syncthreads();

    float ua[8] = {0,0,0,0,0,0,0,0};       // u[h][e] = attn @ t  (thread = e)
    for (int j = 0; j < K_; ++j) {
        float tv = bf2f(*(const unsigned short*)(tg + ((j * 512 + t * 2) ^ ((j & 7) << 4))));
        #pragma unroll
        for (int h = 0; h < 8; ++h) ua[h] += sc[h * K_ + j] * tv;
    }
    #pragma unroll
    for (int h = 0; h < 8; ++h) ul[h * D_ + t] = ua[h];
    __syncthreads();

    {   // pooled[c] = u[h,:] @ Wv[:, c] + bv  (c = t, h = c>>5)
        int h = t >> 5;
        const float* up = ul + h * D_;
        float p = bv[t];
        for (int e = 0; e < D_; ++e) p += up[e] * Wv[e * D_ + t];
        pool_lds[t] = p;
    }
    __syncthreads();
    float po = bo[t];
    for (int e = 0; e < D_; ++e) po += pool_lds[e] * Wo[e * D_ + t];

    // LN (g_pn)
    float s1 = po, q1 = po * po;
    #pragma unroll
    for (int m = 1; m < 64; m <<= 1) { s1 += __shfl_xor(s1, m); q1 += __shfl_xor(q1, m); }
    if (!lane) { redf[wid] = s1; redf[4 + wid] = q1; }
    __syncthreads();
    s1 = redf[0] + redf[1] + redf[2] + redf[3];
    q1 = redf[4] + redf[5] + redf[6] + redf[7];
    float mean = s1 * (1.f/256.f);
    float var = q1 * (1.f/256.f) - mean * mean;
    float rs = rsqrtf(var + 1e-5f);
    float pl = (po - mean) * rs * g_pn[t] + bt_pn[t];
    __syncthreads();

    // combine with weighted average, final LN (g_on)
    float x = wavg[(size_t)blk * D_ + t] / asum[blk] + pl;
    float s2 = x, q2 = x * x;
    #pragma unroll
    for (int m = 1; m < 64; m <<= 1) { s2 += __shfl_xor(s2, m); q2 += __shfl_xor(q2, m); }
    if (!lane) { redf[wid] = s2; redf[4 + wid] = q2; }
    __syncthreads();
    s2 = redf[0] + redf[1] + redf[2] + redf[3];
    q2 = redf[4] + redf[5] + redf[6] + redf[7];
    float mean2 = s2 * (1.f/256.f);
    float var2 = q2 * (1.f/256.f) - mean2 * mean2;
    float rs2 = rsqrtf(var2 + 1e-5f);
    outp[(size_t)blk * D_ + t] = (x - mean2) * rs2 * g_on[t] + bt_on[t];
}

extern "C" void kernel_launch(void* const* d_in, const int* in_sizes, int n_in,
                              void* d_out, int out_size, void* d_ws, size_t ws_size,
                              hipStream_t stream) {
    const float* act    = (const float*)d_in[0];
    const float* tokens = (const float*)d_in[1];
    const float* W_tok  = (const float*)d_in[2];
    const float* b_tok  = (const float*)d_in[3];
    const float* g_tn   = (const float*)d_in[4];
    const float* bt_tn  = (const float*)d_in[5];
    const float* pq     = (const float*)d_in[6];
    const float* Wq     = (const float*)d_in[7];
    const float* bq     = (const float*)d_in[8];
    const float* Wk     = (const float*)d_in[9];
    const float* bk     = (const float*)d_in[10];
    const float* Wv     = (const float*)d_in[11];
    const float* bv     = (const float*)d_in[12];
    const float* Wo     = (const float*)d_in[13];
    const float* bo     = (const float*)d_in[14];
    const float* g_pn   = (const float*)d_in[15];
    const float* bt_pn  = (const float*)d_in[16];
    const float* g_on   = (const float*)d_in[17];
    const float* bt_on  = (const float*)d_in[18];

    char* ws = (char*)d_ws;
    unsigned short* wtb   = (unsigned short*)ws;                         // 1 MB
    float*          tpraw = (float*)(ws + 1048576);                      // 32 MB
    unsigned short* tp    = (unsigned short*)(ws + 1048576 + 33554432);  // 16 MB
    char* p2 = ws + 1048576 + 33554432 + 16777216;
    int*   tidx = (int*)p2;                  // 409600
    float* asum = (float*)(p2 + 409600);     // 3200
    float* wavg = (float*)(p2 + 412800);     // 819200
    float* qW   = (float*)(p2 + 1232000);    // 8192
    float* qb   = (float*)(p2 + 1240192);    // 32

    hipMemsetAsync(wavg, 0, (size_t)B_ * O_ * D_ * sizeof(float), stream);
    k_wtokprep<<<2048, 256, 0, stream>>>(W_tok, wtb);
    k_gemm1<<<M_ / 128, 512, 0, stream>>>(tokens, wtb, tpraw);
    k_ln1<<<M_ / 4, 256, 0, stream>>>(tpraw, b_tok, g_tn, bt_tn, tp);
    k_topk<<<B_ * O_, 256, 0, stream>>>(act, tidx, asum);
    k_wavg<<<dim3(32, 8), 256, 0, stream>>>(act, tp, wavg);
    k_qwprep<<<1, 256, 0, stream>>>(pq, Wq, bq, Wk, bk, qW, qb);
    k_attn<<<B_ * O_, 256, 0, stream>>>(tp, tidx, qW, qb, Wv, bv, Wo, bo,
                                        g_pn, bt_pn, g_on, bt_on, wavg, asum,
                                        (float*)d_out);
}

// Round 2
// 353.177 us; speedup vs baseline: 1.0190x; 1.0190x over previous
//
#include <hip/hip_runtime.h>
#include <hip/hip_bf16.h>

#define DEVI static __device__ __forceinline__

typedef __attribute__((ext_vector_type(8))) short short8;
typedef __attribute__((ext_vector_type(4))) float f32x4;

#define B_   8
#define O_   100
#define N_   4096
#define TOKD 2048
#define D_   256
#define K_   128
#define H_   8
#define M_   (B_*N_)   // 32768

DEVI unsigned short f2bf(float f) {
    unsigned u = __float_as_uint(f);
    u = (u + 0x7FFFu + ((u >> 16) & 1u)) >> 16;   // RNE
    return (unsigned short)u;
}
DEVI float bf2f(unsigned v) { return __uint_as_float(v << 16); }

// ---------- W_tok -> bf16, transposed to [n=256][k=2048] ----------
__global__ __launch_bounds__(256) void k_wtokprep(const float* __restrict__ W,
                                                  unsigned short* __restrict__ wtb) {
    int idx = blockIdx.x * 256 + threadIdx.x;
    int k = idx >> 8;
    int n = idx & 255;
    wtb[n * TOKD + k] = f2bf(W[idx]);
}

// ---------- GEMM1 + bias + LN fused: tp[M,256] = LN(tokens@W_tok + b_tok) in bf16 ----------
// N-tile == 256 == D, so every block owns complete output rows -> LN is block-local.
__global__ __launch_bounds__(512) void k_gemm1(const float* __restrict__ A,
                                               const unsigned short* __restrict__ Bt,
                                               const float* __restrict__ btok,
                                               const float* __restrict__ g,
                                               const float* __restrict__ bt,
                                               unsigned short* __restrict__ tp) {
    // smem: staging (As 10KB + Bs 20KB) during main loop; 64x260 f32 (66.6KB) in epilogue
    __shared__ __align__(16) char smem[66560];
    char* As = smem;            // 128 rows * 80B (32 bf16 + 16B pad)
    char* Bs = smem + 10240;    // 256 rows * 80B
    const int t = threadIdx.x;
    const int bm = blockIdx.x;
    const int lane = t & 63, w = t >> 6;
    const int wm = w >> 2, wn = w & 3;       // wave tile 64x64 in 128x256 block tile
    const int lr = lane >> 4, lc = lane & 15;

    const int ar = t >> 2, ako = (t & 3) * 8;     // A staging: 8 f32/thread
    const int bn = t >> 1, bko = (t & 1) * 16;    // B staging: 16 bf16/thread
    const float* aptr = A + (size_t)(bm * 128 + ar) * TOKD + ako;
    const unsigned short* bptr = Bt + (size_t)bn * TOKD + bko;

    float4 a0 = *(const float4*)(aptr);
    float4 a1 = *(const float4*)(aptr + 4);
    uint4  b0 = *(const uint4*)(bptr);
    uint4  b1 = *(const uint4*)(bptr + 8);

    f32x4 acc[4][4] = {};
    char* aw = As + ar * 80 + ako * 2;
    char* bw = Bs + bn * 80 + bko * 2;
    const char* arow = As + (wm * 64 + lc) * 80 + lr * 16;
    const char* brow = Bs + (wn * 64 + lc) * 80 + lr * 16;

    for (int kt = 0; kt < TOKD / 32; ++kt) {
        uint4 av;
        av.x = f2bf(a0.x) | ((unsigned)f2bf(a0.y) << 16);
        av.y = f2bf(a0.z) | ((unsigned)f2bf(a0.w) << 16);
        av.z = f2bf(a1.x) | ((unsigned)f2bf(a1.y) << 16);
        av.w = f2bf(a1.z) | ((unsigned)f2bf(a1.w) << 16);
        *(uint4*)aw = av;
        *(uint4*)bw = b0;
        *(uint4*)(bw + 16) = b1;
        if (kt < TOKD / 32 - 1) {   // prefetch next K-step into regs (overlaps MFMA)
            const float* ap = aptr + (kt + 1) * 32;
            a0 = *(const float4*)(ap);
            a1 = *(const float4*)(ap + 4);
            const unsigned short* bp = bptr + (kt + 1) * 32;
            b0 = *(const uint4*)(bp);
            b1 = *(const uint4*)(bp + 8);
        }
        __syncthreads();
        short8 af[4], bfv[4];
        #pragma unroll
        for (int mi = 0; mi < 4; ++mi) af[mi] = *(const short8*)(arow + mi * 16 * 80);
        #pragma unroll
        for (int ni = 0; ni < 4; ++ni) bfv[ni] = *(const short8*)(brow + ni * 16 * 80);
        #pragma unroll
        for (int mi = 0; mi < 4; ++mi)
            #pragma unroll
            for (int ni = 0; ni < 4; ++ni)
                acc[mi][ni] = __builtin_amdgcn_mfma_f32_16x16x32_bf16(af[mi], bfv[ni], acc[mi][ni], 0, 0, 0);
        __syncthreads();
    }

    // ---- fused epilogue: bias + LN + bf16 store (stride 260 f32: writes 2-way=free, reads linear)
    float* ep = (float*)smem;
    const int col0 = lane * 4;
    float4 b4 = *(const float4*)(btok + col0);
    float4 g4 = *(const float4*)(g + col0);
    float4 t4 = *(const float4*)(bt + col0);
    #pragma unroll
    for (int chunk = 0; chunk < 2; ++chunk) {
        if (wm == chunk) {
            #pragma unroll
            for (int mi = 0; mi < 4; ++mi)
                #pragma unroll
                for (int ni = 0; ni < 4; ++ni)
                    #pragma unroll
                    for (int r = 0; r < 4; ++r)
                        ep[(mi * 16 + lr * 4 + r) * 260 + wn * 64 + ni * 16 + lc] = acc[mi][ni][r];
        }
        __syncthreads();
        #pragma unroll
        for (int rr = 0; rr < 8; ++rr) {
            int row = w * 8 + rr;
            float4 x4 = *(const float4*)(ep + row * 260 + col0);
            float x0 = x4.x + b4.x, x1 = x4.y + b4.y, x2 = x4.z + b4.z, x3 = x4.w + b4.w;
            float s = x0 + x1 + x2 + x3;
            float q = x0*x0 + x1*x1 + x2*x2 + x3*x3;
            #pragma unroll
            for (int m = 1; m < 64; m <<= 1) { s += __shfl_xor(s, m); q += __shfl_xor(q, m); }
            float mean = s * (1.f/256.f);
            float var = q * (1.f/256.f) - mean * mean;
            float rs = rsqrtf(var + 1e-5f);
            ushort4 o;
            o.x = f2bf((x0-mean)*rs*g4.x + t4.x);
            o.y = f2bf((x1-mean)*rs*g4.y + t4.y);
            o.z = f2bf((x2-mean)*rs*g4.z + t4.z);
            o.w = f2bf((x3-mean)*rs*g4.w + t4.w);
            *(ushort4*)(tp + (size_t)(bm * 128 + chunk * 64 + row) * D_ + col0) = o;
        }
        __syncthreads();
    }
}

// ---------- top-128 per (b,o) row (exact jax tie-break) + row sum ----------
__global__ __launch_bounds__(256) void k_topk(const float* __restrict__ act,
                                              int* __restrict__ oidx,
                                              float* __restrict__ asum) {
    __shared__ float redf[4];
    __shared__ int redi[4];
    __shared__ int cnts[2];
    __shared__ int eql[4096];
    const int t = threadIdx.x, lane = t & 63, wid = t >> 6;
    const int blk = blockIdx.x;
    const float* rp = act + (size_t)blk * N_;
    unsigned v[16];
    float fs = 0.f;
    #pragma unroll
    for (int i = 0; i < 16; ++i) {
        float f = rp[t + i * 256];
        v[i] = __float_as_uint(f);   // non-negative floats: bits order-preserving
        fs += f;
    }
    if (t == 0) { cnts[0] = 0; cnts[1] = 0; }
    #pragma unroll
    for (int m = 1; m < 64; m <<= 1) fs += __shfl_xor(fs, m);
    if (!lane) redf[wid] = fs;
    __syncthreads();
    if (t == 0) asum[blk] = fmaxf(redf[0] + redf[1] + redf[2] + redf[3], 1e-8f);

    unsigned thr = 0u;
    for (int bit = 31; bit >= 0; --bit) {
        unsigned cand = thr | (1u << bit);
        int c = 0;
        #pragma unroll
        for (int i = 0; i < 16; ++i) c += (v[i] >= cand) ? 1 : 0;
        #pragma unroll
        for (int m = 1; m < 64; m <<= 1) c += __shfl_xor(c, m);
        __syncthreads();
        if (!lane) redi[wid] = c;
        __syncthreads();
        int tot = redi[0] + redi[1] + redi[2] + redi[3];
        if (tot >= K_) thr = cand;
    }
    #pragma unroll
    for (int i = 0; i < 16; ++i) {
        unsigned x = v[i];
        if (x > thr) {
            int p = atomicAdd(&cnts[0], 1);
            oidx[blk * K_ + p] = t + i * 256;
        } else if (x == thr) {
            int p = atomicAdd(&cnts[1], 1);
            eql[p] = t + i * 256;
        }
    }
    __syncthreads();
    const int g = cnts[0], E = cnts[1], m = K_ - g;   // ties: lowest index first (jax)
    int last = -1;
    for (int slot = 0; slot < m; ++slot) {
        int best = 0x7FFFFFFF;
        for (int i = t; i < E; i += 256) {
            int e = eql[i];
            if (e > last && e < best) best = e;
        }
        #pragma unroll
        for (int mm = 1; mm < 64; mm <<= 1) best = min(best, __shfl_xor(best, mm));
        __syncthreads();
        if (!lane) redi[wid] = best;
        __syncthreads();
        best = min(min(redi[0], redi[1]), min(redi[2], redi[3]));
        if (t == 0) oidx[blk * K_ + g + slot] = best;
        last = best;
    }
}

// ---------- weighted-average branch: per-(b,kc) partials, no atomics, no init ----------
__global__ __launch_bounds__(256) void k_wavg(const float* __restrict__ act,
                                              const unsigned short* __restrict__ tp,
                                              float* __restrict__ partial) {
    const int kc = blockIdx.x;   // 32 chunks of 128 n
    const int b = blockIdx.y;    // 8
    const int d = threadIdx.x;
    const unsigned short* tpb = tp + ((size_t)b * N_ + kc * 128) * D_ + d;
    const float* actb = act + (size_t)b * O_ * N_ + kc * 128;
    float* pout = partial + ((size_t)(b * 32 + kc) * O_) * D_ + d;
    for (int oc = 0; oc < 10; ++oc) {
        float acc[10] = {};
        for (int q = 0; q < 32; ++q) {
            float t0 = bf2f(tpb[(q * 4 + 0) * D_]);
            float t1 = bf2f(tpb[(q * 4 + 1) * D_]);
            float t2 = bf2f(tpb[(q * 4 + 2) * D_]);
            float t3 = bf2f(tpb[(q * 4 + 3) * D_]);
            #pragma unroll
            for (int oj = 0; oj < 10; ++oj) {
                float4 a4 = *(const float4*)(actb + (size_t)(oc * 10 + oj) * N_ + q * 4);
                acc[oj] += a4.x * t0 + a4.y * t1 + a4.z * t2 + a4.w * t3;
            }
        }
        #pragma unroll
        for (int oj = 0; oj < 10; ++oj)
            pout[(size_t)(oc * 10 + oj) * D_] = acc[oj];
    }
}

// ---------- fold Wq/Wk through the shared query: qW[h,e], qb[h] ----------
__global__ __launch_bounds__(256) void k_qwprep(const float* __restrict__ pq,
    const float* __restrict__ Wq, const float* __restrict__ bq,
    const float* __restrict__ Wk, const float* __restrict__ bk,
    float* __restrict__ qW, float* __restrict__ qb) {
    __shared__ float qh[D_];
    const int t = threadIdx.x;
    float s = bq[t];
    for (int e = 0; e < D_; ++e) s += pq[e] * Wq[e * D_ + t];
    qh[t] = s;
    __syncthreads();
    #pragma unroll
    for (int h = 0; h < 8; ++h) {
        float u = 0.f;
        #pragma unroll
        for (int dd = 0; dd < 32; ++dd) u += qh[h * 32 + dd] * Wk[t * D_ + h * 32 + dd];
        qW[h * D_ + t] = u;
    }
    if (t < 8) {
        float u = 0.f;
        for (int dd = 0; dd < 32; ++dd) u += qh[t * 32 + dd] * bk[t * 32 + dd];
        qb[t] = u;
    }
}

// ---------- gather + attention + Wv/Wo + LN + combine + final LN ----------
__global__ __launch_bounds__(256) void k_attn(
    const unsigned short* __restrict__ tp, const int* __restrict__ oidx,
    const float* __restrict__ qW, const float* __restrict__ qb,
    const float* __restrict__ Wv, const float* __restrict__ bv,
    const float* __restrict__ Wo, const float* __restrict__ bo,
    const float* __restrict__ g_pn, const float* __restrict__ bt_pn,
    const float* __restrict__ g_on, const float* __restrict__ bt_on,
    const float* __restrict__ partial, const float* __restrict__ asum,
    float* __restrict__ outp)
{
    __shared__ uint4 tgU[4096];      // 128 rows x 512B, XOR-swizzled
    __shared__ float sc[H_ * K_];
    __shared__ float ul[H_ * D_];
    __shared__ float pool_lds[D_];
    __shared__ float redf[8];
    __shared__ int idxl[K_];
    char* tg = (char*)tgU;

    const int t = threadIdx.x, lane = t & 63, wid = t >> 6;
    const int blk = blockIdx.x;
    const int b = blk / O_;
    const int o = blk - b * O_;

    if (t < K_) idxl[t] = oidx[blk * K_ + t];
    __syncthreads();

    #pragma unroll
    for (int it = 0; it < 16; ++it) {      // gather top-128 token rows (bf16)
        int c = t + it * 256;
        int j = c >> 5, ch = c & 31;
        uint4 v = *(const uint4*)(tp + ((size_t)(b * N_ + idxl[j])) * D_ + ch * 8);
        *(uint4*)(tg + ((j * 512 + ch * 16) ^ ((j & 7) << 4))) = v;
    }
    __syncthreads();

    #pragma unroll
    for (int kk = 0; kk < 4; ++kk) {       // scores[h][j] = t.qW + qb, /sqrt(32)
        int oid = t + kk * 256;
        int h = oid >> 7, j = oid & 127;
        const float* qr = qW + h * D_;
        float s = 0.f;
        #pragma unroll 4
        for (int e8 = 0; e8 < 32; ++e8) {
            uint4 tv = *(const uint4*)(tg + ((j * 512 + e8 * 16) ^ ((j & 7) << 4)));
            const float* qe = qr + e8 * 8;
            s += bf2f(tv.x & 0xffffu) * qe[0] + bf2f(tv.x >> 16) * qe[1]
               + bf2f(tv.y & 0xffffu) * qe[2] + bf2f(tv.y >> 16) * qe[3]
               + bf2f(tv.z & 0xffffu) * qe[4] + bf2f(tv.z >> 16) * qe[5]
               + bf2f(tv.w & 0xffffu) * qe[6] + bf2f(tv.w >> 16) * qe[7];
        }
        sc[h * K_ + j] = (s + qb[h]) * 0.1767766952966369f;
    }
    __syncthreads();

    #pragma unroll
    for (int hh = 0; hh < 2; ++hh) {       // softmax per head (wave handles 2 heads)
        int h = wid * 2 + hh;
        float v0 = sc[h * K_ + lane], v1 = sc[h * K_ + 64 + lane];
        float mx = fmaxf(v0, v1);
        #pragma unroll
        for (int m = 1; m < 64; m <<= 1) mx = fmaxf(mx, __shfl_xor(mx, m));
        float e0 = __expf(v0 - mx), e1 = __expf(v1 - mx);
        float ss = e0 + e1;
        #pragma unroll
        for (int m = 1; m < 64; m <<= 1) ss += __shfl_xor(ss, m);
        float inv = 1.0f / ss;
        sc[h * K_ + lane] = e0 * inv;
        sc[h * K_ + 64 + lane] = e1 * inv;
    }
    __syncthreads();

    float ua[8] = {0,0,0,0,0,0,0,0};       // u[h][e] = attn @ t  (thread = e)
    for (int j = 0; j < K_; ++j) {
        float tv = bf2f(*(const unsigned short*)(tg + ((j * 512 + t * 2) ^ ((j & 7) << 4))));
        #pragma unroll
        for (int h = 0; h < 8; ++h) ua[h] += sc[h * K_ + j] * tv;
    }
    #pragma unroll
    for (int h = 0; h < 8; ++h) ul[h * D_ + t] = ua[h];
    __syncthreads();

    {   // pooled[c] = u[h,:] @ Wv[:, c] + bv  (c = t, h = c>>5)
        int h = t >> 5;
        const float* up = ul + h * D_;
        float p = bv[t];
        for (int e = 0; e < D_; ++e) p += up[e] * Wv[e * D_ + t];
        pool_lds[t] = p;
    }
    __syncthreads();
    float po = bo[t];
    for (int e = 0; e < D_; ++e) po += pool_lds[e] * Wo[e * D_ + t];

    // LN (g_pn)
    float s1 = po, q1 = po * po;
    #pragma unroll
    for (int m = 1; m < 64; m <<= 1) { s1 += __shfl_xor(s1, m); q1 += __shfl_xor(q1, m); }
    if (!lane) { redf[wid] = s1; redf[4 + wid] = q1; }
    __syncthreads();
    s1 = redf[0] + redf[1] + redf[2] + redf[3];
    q1 = redf[4] + redf[5] + redf[6] + redf[7];
    float mean = s1 * (1.f/256.f);
    float var = q1 * (1.f/256.f) - mean * mean;
    float rs = rsqrtf(var + 1e-5f);
    float pl = (po - mean) * rs * g_pn[t] + bt_pn[t];
    __syncthreads();

    // combine with weighted average (sum 32 partials), final LN (g_on)
    float wa = 0.f;
    const float* pp = partial + ((size_t)(b * 32) * O_ + o) * D_ + t;
    #pragma unroll 8
    for (int kc = 0; kc < 32; ++kc) wa += pp[(size_t)kc * O_ * D_];
    float x = wa / asum[blk] + pl;
    float s2 = x, q2 = x * x;
    #pragma unroll
    for (int m = 1; m < 64; m <<= 1) { s2 += __shfl_xor(s2, m); q2 += __shfl_xor(q2, m); }
    if (!lane) { redf[wid] = s2; redf[4 + wid] = q2; }
    __syncthreads();
    s2 = redf[0] + redf[1] + redf[2] + redf[3];
    q2 = redf[4] + redf[5] + redf[6] + redf[7];
    float mean2 = s2 * (1.f/256.f);
    float var2 = q2 * (1.f/256.f) - mean2 * mean2;
    float rs2 = rsqrtf(var2 + 1e-5f);
    outp[(size_t)blk * D_ + t] = (x - mean2) * rs2 * g_on[t] + bt_on[t];
}

extern "C" void kernel_launch(void* const* d_in, const int* in_sizes, int n_in,
                              void* d_out, int out_size, void* d_ws, size_t ws_size,
                              hipStream_t stream) {
    const float* act    = (const float*)d_in[0];
    const float* tokens = (const float*)d_in[1];
    const float* W_tok  = (const float*)d_in[2];
    const float* b_tok  = (const float*)d_in[3];
    const float* g_tn   = (const float*)d_in[4];
    const float* bt_tn  = (const float*)d_in[5];
    const float* pq     = (const float*)d_in[6];
    const float* Wq     = (const float*)d_in[7];
    const float* bq     = (const float*)d_in[8];
    const float* Wk     = (const float*)d_in[9];
    const float* bk     = (const float*)d_in[10];
    const float* Wv     = (const float*)d_in[11];
    const float* bv     = (const float*)d_in[12];
    const float* Wo     = (const float*)d_in[13];
    const float* bo     = (const float*)d_in[14];
    const float* g_pn   = (const float*)d_in[15];
    const float* bt_pn  = (const float*)d_in[16];
    const float* g_on   = (const float*)d_in[17];
    const float* bt_on  = (const float*)d_in[18];

    char* ws = (char*)d_ws;
    unsigned short* wtb   = (unsigned short*)ws;                 // 1 MB
    unsigned short* tp    = (unsigned short*)(ws + 1048576);     // 16 MB
    int*   tidx = (int*)(ws + 17825792);                         // 409600
    float* asum = (float*)(ws + 18235392);                       // 3200
    float* part = (float*)(ws + 18238592);                       // 26.2 MB
    float* qW   = (float*)(ws + 44452992);                       // 8192
    float* qb   = (float*)(ws + 44461184);                       // 32

    k_wtokprep<<<2048, 256, 0, stream>>>(W_tok, wtb);
    k_gemm1<<<M_ / 128, 512, 0, stream>>>(tokens, wtb, b_tok, g_tn, bt_tn, tp);
    k_topk<<<B_ * O_, 256, 0, stream>>>(act, tidx, asum);
    k_wavg<<<dim3(32, 8), 256, 0, stream>>>(act, tp, part);
    k_qwprep<<<1, 256, 0, stream>>>(pq, Wq, bq, Wk, bk, qW, qb);
    k_attn<<<B_ * O_, 256, 0, stream>>>(tp, tidx, qW, qb, Wv, bv, Wo, bo,
                                        g_pn, bt_pn, g_on, bt_on, part, asum,
                                        (float*)d_out);
}

// Round 3
// 272.280 us; speedup vs baseline: 1.3218x; 1.2971x over previous
//
#include <hip/hip_runtime.h>
#include <hip/hip_bf16.h>

#define DEVI static __device__ __forceinline__

typedef __attribute__((ext_vector_type(8))) short short8;
typedef __attribute__((ext_vector_type(4))) float f32x4;

#define B_   8
#define O_   100
#define N_   4096
#define TOKD 2048
#define D_   256
#define K_   128
#define H_   8
#define M_   (B_*N_)   // 32768

DEVI unsigned short f2bf(float f) {
    unsigned u = __float_as_uint(f);
    u = (u + 0x7FFFu + ((u >> 16) & 1u)) >> 16;   // RNE
    return (unsigned short)u;
}
DEVI float bf2f(unsigned v) { return __uint_as_float(v << 16); }

DEVI unsigned pkbf(float lo, float hi) {   // packed RNE f32->bf16 pair (1 VALU op)
    unsigned r;
    asm("v_cvt_pk_bf16_f32 %0, %1, %2" : "=v"(r) : "v"(lo), "v"(hi));
    return r;
}
DEVI short8 pack8(f32x4 x, f32x4 y) {
    union { unsigned u[4]; short8 s; } r;
    r.u[0] = pkbf(x[0], x[1]); r.u[1] = pkbf(x[2], x[3]);
    r.u[2] = pkbf(y[0], y[1]); r.u[3] = pkbf(y[2], y[3]);
    return r.s;
}
DEVI void gload16(const void* g, void* l) {   // async global->LDS, 16B/lane
    __builtin_amdgcn_global_load_lds((const __attribute__((address_space(1))) void*)g,
                                     (__attribute__((address_space(3))) void*)l, 16, 0, 0);
}

// ---------- W_tok -> bf16, transposed to [n=256][k=2048] ----------
__global__ __launch_bounds__(256) void k_wtokprep(const float* __restrict__ W,
                                                  unsigned short* __restrict__ wtb) {
    int idx = blockIdx.x * 256 + threadIdx.x;
    int k = idx >> 8;
    int n = idx & 255;
    wtb[n * TOKD + k] = f2bf(W[idx]);
}

// ---------- GEMM1 + bias + LN fused (gload_lds 2-phase dbuf pipeline) ----------
// A f32 staged raw into LDS (cast on read via cvt_pk); B bf16. BK=64, 512 thr.
__global__ __launch_bounds__(512) void k_gemm1(const float* __restrict__ A,
                                               const unsigned short* __restrict__ Bt,
                                               const float* __restrict__ btok,
                                               const float* __restrict__ g,
                                               const float* __restrict__ bt,
                                               unsigned short* __restrict__ tp) {
    // A bufs: [0,32K),[32K,64K) ; B bufs: [64K,96K),[96K,128K). Epilogue reuses [0,66.6K).
    __shared__ __align__(16) char smem[131072];
    const int t = threadIdx.x;
    const int bm = blockIdx.x;
    const int lane = t & 63, w = t >> 6;
    const int wm = w >> 2, wn = w & 3;       // 2x4 waves, wave tile 64x64
    const int lr = lane >> 4, lc = lane & 15;

    // staging source addresses (pre-swizzled global so linear-LDS == swizzled layout)
    // A: LDS[row][cB] = A[grow][kt*64 + ((cB ^ ((row&7)<<5))>>2)], row=c*32+(t>>4), cB=(t&15)*16
    const float* ag = A + (size_t)(bm * 128 + (t >> 4)) * TOKD
                        + (((((t & 15) << 4)) ^ (((t >> 4) & 7) << 5)) >> 2);
    // B: LDS[n][cB] = Bt[n][kt*64 + ((cB ^ ((n&7)<<4))>>1)], n=c*64+(t>>3), cB=(t&7)*16
    const unsigned short* bg = Bt + (size_t)(t >> 3) * TOKD
                        + (((((t & 7) << 4)) ^ (((t >> 3) & 7) << 4)) >> 1);
    char* ldsw = smem + (t >> 6) * 1024;     // wave-uniform base (+lane*16 implicit)

    f32x4 acc[4][4] = {};
    const int NT = TOKD / 64;   // 32

    // prologue: stage tile 0 into buf 0
    #pragma unroll
    for (int c = 0; c < 4; ++c) gload16(ag + (size_t)c * 32 * TOKD, ldsw + c * 8192);
    #pragma unroll
    for (int c = 0; c < 4; ++c) gload16(bg + (size_t)c * 64 * TOKD, ldsw + 65536 + c * 8192);

    int cur = 0;
    for (int kt = 0; kt < NT; ++kt) {
        asm volatile("s_waitcnt vmcnt(0)" ::: "memory");
        __syncthreads();
        if (kt + 1 < NT) {   // stage next tile into other buffer (in flight across MFMA)
            const float* an = ag + (size_t)(kt + 1) * 64;
            const unsigned short* bn = bg + (size_t)(kt + 1) * 64;
            char* dst = ldsw + (cur ^ 1) * 32768;
            #pragma unroll
            for (int c = 0; c < 4; ++c) gload16(an + (size_t)c * 32 * TOKD, dst + c * 8192);
            #pragma unroll
            for (int c = 0; c < 4; ++c) gload16(bn + (size_t)c * 64 * TOKD, dst + 65536 + c * 8192);
        }
        const char* Ab = smem + cur * 32768;
        const char* Bb = smem + 65536 + cur * 32768;
        #pragma unroll
        for (int kk = 0; kk < 2; ++kk) {
            short8 afr[4], bfr[4];
            #pragma unroll
            for (int mi = 0; mi < 4; ++mi) {
                int row = wm * 64 + mi * 16 + lc;
                int sw = (row & 7) << 5;
                int cb = kk * 128 + lr * 32;
                f32x4 x = *(const f32x4*)(Ab + row * 256 + (cb ^ sw));
                f32x4 y = *(const f32x4*)(Ab + row * 256 + ((cb + 16) ^ sw));
                afr[mi] = pack8(x, y);
            }
            #pragma unroll
            for (int ni = 0; ni < 4; ++ni) {
                int n = wn * 64 + ni * 16 + lc;
                bfr[ni] = *(const short8*)(Bb + n * 128 + ((kk * 64 + lr * 16) ^ ((n & 7) << 4)));
            }
            #pragma unroll
            for (int mi = 0; mi < 4; ++mi)
                #pragma unroll
                for (int ni = 0; ni < 4; ++ni)
                    acc[mi][ni] = __builtin_amdgcn_mfma_f32_16x16x32_bf16(afr[mi], bfr[ni], acc[mi][ni], 0, 0, 0);
        }
        cur ^= 1;
    }
    __syncthreads();

    // ---- fused epilogue: bias + LN + bf16 store
    float* ep = (float*)smem;
    const int col0 = lane * 4;
    float4 b4 = *(const float4*)(btok + col0);
    float4 g4 = *(const float4*)(g + col0);
    float4 t4 = *(const float4*)(bt + col0);
    #pragma unroll
    for (int chunk = 0; chunk < 2; ++chunk) {
        if (wm == chunk) {
            #pragma unroll
            for (int mi = 0; mi < 4; ++mi)
                #pragma unroll
                for (int ni = 0; ni < 4; ++ni)
                    #pragma unroll
                    for (int r = 0; r < 4; ++r)
                        ep[(mi * 16 + lr * 4 + r) * 260 + wn * 64 + ni * 16 + lc] = acc[mi][ni][r];
        }
        __syncthreads();
        #pragma unroll
        for (int rr = 0; rr < 8; ++rr) {
            int row = w * 8 + rr;
            float4 x4 = *(const float4*)(ep + row * 260 + col0);
            float x0 = x4.x + b4.x, x1 = x4.y + b4.y, x2 = x4.z + b4.z, x3 = x4.w + b4.w;
            float s = x0 + x1 + x2 + x3;
            float q = x0*x0 + x1*x1 + x2*x2 + x3*x3;
            #pragma unroll
            for (int m = 1; m < 64; m <<= 1) { s += __shfl_xor(s, m); q += __shfl_xor(q, m); }
            float mean = s * (1.f/256.f);
            float var = q * (1.f/256.f) - mean * mean;
            float rs = rsqrtf(var + 1e-5f);
            ushort4 o;
            o.x = f2bf((x0-mean)*rs*g4.x + t4.x);
            o.y = f2bf((x1-mean)*rs*g4.y + t4.y);
            o.z = f2bf((x2-mean)*rs*g4.z + t4.z);
            o.w = f2bf((x3-mean)*rs*g4.w + t4.w);
            *(ushort4*)(tp + (size_t)(bm * 128 + chunk * 64 + row) * D_ + col0) = o;
        }
        __syncthreads();
    }
}

// ---------- top-128 per (b,o) row (exact jax tie-break) + row sum ----------
__global__ __launch_bounds__(256) void k_topk(const float* __restrict__ act,
                                              int* __restrict__ oidx,
                                              float* __restrict__ asum) {
    __shared__ float redf[4];
    __shared__ int redi[4];
    __shared__ int cnts[2];
    __shared__ int eql[4096];
    const int t = threadIdx.x, lane = t & 63, wid = t >> 6;
    const int blk = blockIdx.x;
    const float* rp = act + (size_t)blk * N_;
    unsigned v[16];
    float fs = 0.f;
    #pragma unroll
    for (int i = 0; i < 16; ++i) {
        float f = rp[t + i * 256];
        v[i] = __float_as_uint(f);
        fs += f;
    }
    if (t == 0) { cnts[0] = 0; cnts[1] = 0; }
    #pragma unroll
    for (int m = 1; m < 64; m <<= 1) fs += __shfl_xor(fs, m);
    if (!lane) redf[wid] = fs;
    __syncthreads();
    if (t == 0) asum[blk] = fmaxf(redf[0] + redf[1] + redf[2] + redf[3], 1e-8f);

    unsigned thr = 0u;
    for (int bit = 31; bit >= 0; --bit) {
        unsigned cand = thr | (1u << bit);
        int c = 0;
        #pragma unroll
        for (int i = 0; i < 16; ++i) c += (v[i] >= cand) ? 1 : 0;
        #pragma unroll
        for (int m = 1; m < 64; m <<= 1) c += __shfl_xor(c, m);
        __syncthreads();
        if (!lane) redi[wid] = c;
        __syncthreads();
        int tot = redi[0] + redi[1] + redi[2] + redi[3];
        if (tot >= K_) thr = cand;
    }
    #pragma unroll
    for (int i = 0; i < 16; ++i) {
        unsigned x = v[i];
        if (x > thr) {
            int p = atomicAdd(&cnts[0], 1);
            oidx[blk * K_ + p] = t + i * 256;
        } else if (x == thr) {
            int p = atomicAdd(&cnts[1], 1);
            eql[p] = t + i * 256;
        }
    }
    __syncthreads();
    const int gc = cnts[0], E = cnts[1], m = K_ - gc;
    int last = -1;
    for (int slot = 0; slot < m; ++slot) {
        int best = 0x7FFFFFFF;
        for (int i = t; i < E; i += 256) {
            int e = eql[i];
            if (e > last && e < best) best = e;
        }
        #pragma unroll
        for (int mm = 1; mm < 64; mm <<= 1) best = min(best, __shfl_xor(best, mm));
        __syncthreads();
        if (!lane) redi[wid] = best;
        __syncthreads();
        best = min(min(redi[0], redi[1]), min(redi[2], redi[3]));
        if (t == 0) oidx[blk * K_ + gc + slot] = best;
        last = best;
    }
}

// ---------- weighted-average partials (grid z-split x5 for occupancy) ----------
__global__ __launch_bounds__(256) void k_wavg(const float* __restrict__ act,
                                              const unsigned short* __restrict__ tp,
                                              float* __restrict__ partial) {
    const int kc = blockIdx.x;   // 32 chunks of 128 n
    const int b = blockIdx.y;    // 8
    const int d = threadIdx.x;
    const unsigned short* tpb = tp + ((size_t)b * N_ + kc * 128) * D_ + d;
    const float* actb = act + (size_t)b * O_ * N_ + kc * 128;
    float* pout = partial + ((size_t)(b * 32 + kc) * O_) * D_ + d;
    for (int oci = 0; oci < 2; ++oci) {
        const int oc = blockIdx.z * 2 + oci;
        float acc[10] = {};
        for (int q = 0; q < 32; ++q) {
            float t0 = bf2f(tpb[(q * 4 + 0) * D_]);
            float t1 = bf2f(tpb[(q * 4 + 1) * D_]);
            float t2 = bf2f(tpb[(q * 4 + 2) * D_]);
            float t3 = bf2f(tpb[(q * 4 + 3) * D_]);
            #pragma unroll
            for (int oj = 0; oj < 10; ++oj) {   // act addr wave-uniform -> s_load
                float4 a4 = *(const float4*)(actb + (size_t)(oc * 10 + oj) * N_ + q * 4);
                acc[oj] += a4.x * t0 + a4.y * t1 + a4.z * t2 + a4.w * t3;
            }
        }
        #pragma unroll
        for (int oj = 0; oj < 10; ++oj)
            pout[(size_t)(oc * 10 + oj) * D_] = acc[oj];
    }
}

// ---------- qh partials: qhp[j][t] = sum_{e in [8j,8j+8)} pq[e]*Wq[e][t] ----------
__global__ __launch_bounds__(256) void k_qh(const float* __restrict__ pq,
                                            const float* __restrict__ Wq,
                                            float* __restrict__ qhp) {
    const int j = blockIdx.x, t = threadIdx.x;
    float s = 0.f;
    #pragma unroll
    for (int e = 0; e < 8; ++e) s += pq[j * 8 + e] * Wq[(j * 8 + e) * D_ + t];
    qhp[j * D_ + t] = s;
}

// ---------- per-head fold: qW[h][e] = qh[h*32..]·Wk[e][h*32..], qb[h] ----------
__global__ __launch_bounds__(256) void k_qw(const float* __restrict__ qhp,
                                            const float* __restrict__ bq,
                                            const float* __restrict__ Wk,
                                            const float* __restrict__ bk,
                                            float* __restrict__ qW,
                                            float* __restrict__ qb) {
    __shared__ float qhl[32];
    const int h = blockIdx.x, t = threadIdx.x;
    if (t < 32) {
        float s = bq[h * 32 + t];
        #pragma unroll
        for (int j = 0; j < 32; ++j) s += qhp[j * D_ + h * 32 + t];
        qhl[t] = s;
    }
    __syncthreads();
    float u = 0.f;
    #pragma unroll
    for (int dd = 0; dd < 32; ++dd) u += qhl[dd] * Wk[t * D_ + h * 32 + dd];
    qW[h * D_ + t] = u;
    if (t == 0) {
        float s = 0.f;
        for (int dd = 0; dd < 32; ++dd) s += qhl[dd] * bk[h * 32 + dd];
        qb[h] = s;
    }
}

// ---------- gather + attention + Wv/Wo + LN + combine + final LN ----------
DEVI int swz(int j, int chunk) { return j * 512 + ((chunk ^ (j & 31)) << 4); }

__global__ __launch_bounds__(256) void k_attn(
    const unsigned short* __restrict__ tp, const int* __restrict__ oidx,
    const float* __restrict__ qW, const float* __restrict__ qb,
    const float* __restrict__ Wv, const float* __restrict__ bv,
    const float* __restrict__ Wo, const float* __restrict__ bo,
    const float* __restrict__ g_pn, const float* __restrict__ bt_pn,
    const float* __restrict__ g_on, const float* __restrict__ bt_on,
    const float* __restrict__ partial, const float* __restrict__ asum,
    float* __restrict__ outp)
{
    __shared__ uint4 tgU[4096];      // 128 rows x 512B, (j&31) chunk-XOR swizzle
    __shared__ float sc[H_ * K_];    // [h][j] raw scores
    __shared__ float sc2[K_ * H_];   // [j][h] normalized (PV reads 2 broadcast b128/j)
    __shared__ float ul[H_ * D_];
    __shared__ float pool_lds[D_];
    __shared__ float redf[8];
    __shared__ int idxl[K_];
    char* tg = (char*)tgU;

    const int t = threadIdx.x, lane = t & 63, wid = t >> 6;
    const int blk = blockIdx.x;
    const int b = blk / O_;
    const int o = blk - b * O_;

    if (t < K_) idxl[t] = oidx[blk * K_ + t];
    __syncthreads();

    #pragma unroll
    for (int it = 0; it < 16; ++it) {      // gather top-128 token rows (bf16)
        int c = t + it * 256;
        int j = c >> 5, ch = c & 31;
        uint4 v = *(const uint4*)(tp + ((size_t)(b * N_ + idxl[j])) * D_ + ch * 8);
        *(uint4*)(tg + swz(j, ch)) = v;
    }
    __syncthreads();

    #pragma unroll
    for (int kk = 0; kk < 4; ++kk) {       // scores[h][j]
        int oid = t + kk * 256;
        int h = oid >> 7, j = oid & 127;
        const float* qr = qW + h * D_;
        float s = 0.f;
        #pragma unroll 4
        for (int e8 = 0; e8 < 32; ++e8) {
            uint4 tv = *(const uint4*)(tg + swz(j, e8));
            const float* qe = qr + e8 * 8;
            s += bf2f(tv.x & 0xffffu) * qe[0] + bf2f(tv.x >> 16) * qe[1]
               + bf2f(tv.y & 0xffffu) * qe[2] + bf2f(tv.y >> 16) * qe[3]
               + bf2f(tv.z & 0xffffu) * qe[4] + bf2f(tv.z >> 16) * qe[5]
               + bf2f(tv.w & 0xffffu) * qe[6] + bf2f(tv.w >> 16) * qe[7];
        }
        sc[h * K_ + j] = (s + qb[h]) * 0.1767766952966369f;
    }
    __syncthreads();

    #pragma unroll
    for (int hh = 0; hh < 2; ++hh) {       // softmax; write transposed [j][h]
        int h = wid * 2 + hh;
        float v0 = sc[h * K_ + lane], v1 = sc[h * K_ + 64 + lane];
        float mx = fmaxf(v0, v1);
        #pragma unroll
        for (int m = 1; m < 64; m <<= 1) mx = fmaxf(mx, __shfl_xor(mx, m));
        float e0 = __expf(v0 - mx), e1 = __expf(v1 - mx);
        float ss = e0 + e1;
        #pragma unroll
        for (int m = 1; m < 64; m <<= 1) ss += __shfl_xor(ss, m);
        float inv = 1.0f / ss;
        sc2[lane * H_ + h] = e0 * inv;
        sc2[(64 + lane) * H_ + h] = e1 * inv;
    }
    __syncthreads();

    float ua[8] = {0,0,0,0,0,0,0,0};       // u[h][e] = attn @ t  (thread = e)
    #pragma unroll 4
    for (int j = 0; j < K_; ++j) {
        float tv = bf2f(*(const unsigned short*)(tg + swz(j, t >> 3) + (t & 7) * 2));
        f32x4 w0 = *(const f32x4*)(sc2 + j * H_);
        f32x4 w1 = *(const f32x4*)(sc2 + j * H_ + 4);
        ua[0] += w0[0] * tv; ua[1] += w0[1] * tv; ua[2] += w0[2] * tv; ua[3] += w0[3] * tv;
        ua[4] += w1[0] * tv; ua[5] += w1[1] * tv; ua[6] += w1[2] * tv; ua[7] += w1[3] * tv;
    }
    #pragma unroll
    for (int h = 0; h < 8; ++h) ul[h * D_ + t] = ua[h];
    __syncthreads();

    {   // pooled[c] = u[h,:] @ Wv[:, c] + bv  (c = t, h = c>>5)
        int h = t >> 5;
        const float* up = ul + h * D_;
        float p = bv[t];
        for (int e = 0; e < D_; ++e) p += up[e] * Wv[e * D_ + t];
        pool_lds[t] = p;
    }
    __syncthreads();
    float po = bo[t];
    for (int e = 0; e < D_; ++e) po += pool_lds[e] * Wo[e * D_ + t];

    // LN (g_pn)
    float s1 = po, q1 = po * po;
    #pragma unroll
    for (int m = 1; m < 64; m <<= 1) { s1 += __shfl_xor(s1, m); q1 += __shfl_xor(q1, m); }
    if (!lane) { redf[wid] = s1; redf[4 + wid] = q1; }
    __syncthreads();
    s1 = redf[0] + redf[1] + redf[2] + redf[3];
    q1 = redf[4] + redf[5] + redf[6] + redf[7];
    float mean = s1 * (1.f/256.f);
    float var = q1 * (1.f/256.f) - mean * mean;
    float rs = rsqrtf(var + 1e-5f);
    float pl = (po - mean) * rs * g_pn[t] + bt_pn[t];
    __syncthreads();

    // combine with weighted average (sum 32 partials), final LN (g_on)
    float wa = 0.f;
    const float* pp = partial + ((size_t)(b * 32) * O_ + o) * D_ + t;
    #pragma unroll 8
    for (int kc = 0; kc < 32; ++kc) wa += pp[(size_t)kc * O_ * D_];
    float x = wa / asum[blk] + pl;
    float s2 = x, q2 = x * x;
    #pragma unroll
    for (int m = 1; m < 64; m <<= 1) { s2 += __shfl_xor(s2, m); q2 += __shfl_xor(q2, m); }
    if (!lane) { redf[wid] = s2; redf[4 + wid] = q2; }
    __syncthreads();
    s2 = redf[0] + redf[1] + redf[2] + redf[3];
    q2 = redf[4] + redf[5] + redf[6] + redf[7];
    float mean2 = s2 * (1.f/256.f);
    float var2 = q2 * (1.f/256.f) - mean2 * mean2;
    float rs2 = rsqrtf(var2 + 1e-5f);
    outp[(size_t)blk * D_ + t] = (x - mean2) * rs2 * g_on[t] + bt_on[t];
}

extern "C" void kernel_launch(void* const* d_in, const int* in_sizes, int n_in,
                              void* d_out, int out_size, void* d_ws, size_t ws_size,
                              hipStream_t stream) {
    const float* act    = (const float*)d_in[0];
    const float* tokens = (const float*)d_in[1];
    const float* W_tok  = (const float*)d_in[2];
    const float* b_tok  = (const float*)d_in[3];
    const float* g_tn   = (const float*)d_in[4];
    const float* bt_tn  = (const float*)d_in[5];
    const float* pq     = (const float*)d_in[6];
    const float* Wq     = (const float*)d_in[7];
    const float* bq     = (const float*)d_in[8];
    const float* Wk     = (const float*)d_in[9];
    const float* bk     = (const float*)d_in[10];
    const float* Wv     = (const float*)d_in[11];
    const float* bv     = (const float*)d_in[12];
    const float* Wo     = (const float*)d_in[13];
    const float* bo     = (const float*)d_in[14];
    const float* g_pn   = (const float*)d_in[15];
    const float* bt_pn  = (const float*)d_in[16];
    const float* g_on   = (const float*)d_in[17];
    const float* bt_on  = (const float*)d_in[18];

    char* ws = (char*)d_ws;
    unsigned short* wtb   = (unsigned short*)ws;                 // 1 MB
    unsigned short* tp    = (unsigned short*)(ws + 1048576);     // 16 MB
    int*   tidx = (int*)(ws + 17825792);                         // 409600
    float* asum = (float*)(ws + 18235392);                       // 3200
    float* part = (float*)(ws + 18238592);                       // 26.2 MB
    float* qW   = (float*)(ws + 44452992);                       // 8 KB
    float* qb   = (float*)(ws + 44461184);                       // 32 B
    float* qhp  = (float*)(ws + 44461312);                       // 32 KB

    k_wtokprep<<<2048, 256, 0, stream>>>(W_tok, wtb);
    k_qh<<<32, 256, 0, stream>>>(pq, Wq, qhp);
    k_qw<<<8, 256, 0, stream>>>(qhp, bq, Wk, bk, qW, qb);
    k_gemm1<<<M_ / 128, 512, 0, stream>>>(tokens, wtb, b_tok, g_tn, bt_tn, tp);
    k_topk<<<B_ * O_, 256, 0, stream>>>(act, tidx, asum);
    k_wavg<<<dim3(32, 8, 5), 256, 0, stream>>>(act, tp, part);
    k_attn<<<B_ * O_, 256, 0, stream>>>(tp, tidx, qW, qb, Wv, bv, Wo, bo,
                                        g_pn, bt_pn, g_on, bt_on, part, asum,
                                        (float*)d_out);
}

// Round 4
// 225.224 us; speedup vs baseline: 1.5979x; 1.2089x over previous
//
#include <hip/hip_runtime.h>
#include <hip/hip_bf16.h>

#define DEVI static __device__ __forceinline__

typedef __attribute__((ext_vector_type(8))) short short8;
typedef __attribute__((ext_vector_type(4))) float f32x4;

#define B_   8
#define O_   100
#define N_   4096
#define TOKD 2048
#define D_   256
#define K_   128
#define H_   8
#define M_   (B_*N_)   // 32768

DEVI unsigned short f2bf(float f) {
    unsigned u = __float_as_uint(f);
    u = (u + 0x7FFFu + ((u >> 16) & 1u)) >> 16;   // RNE
    return (unsigned short)u;
}
DEVI float bf2f(unsigned v) { return __uint_as_float(v << 16); }

DEVI unsigned pkbf(float lo, float hi) {   // packed RNE f32->bf16 pair
    unsigned r;
    asm("v_cvt_pk_bf16_f32 %0, %1, %2" : "=v"(r) : "v"(lo), "v"(hi));
    return r;
}
DEVI void gload16(const void* g, void* l) {   // async global->LDS, 16B/lane
    __builtin_amdgcn_global_load_lds((const __attribute__((address_space(1))) void*)g,
                                     (__attribute__((address_space(3))) void*)l, 16, 0, 0);
}

// ---------- merged prep: W_tok->bf16^T (blocks 0..2047) + q-fold (blocks 2048..2055) ----------
__global__ __launch_bounds__(256) void k_prep(const float* __restrict__ W,
                                              unsigned short* __restrict__ wtb,
                                              const float* __restrict__ pq,
                                              const float* __restrict__ Wq,
                                              const float* __restrict__ bqv,
                                              const float* __restrict__ Wk,
                                              const float* __restrict__ bkv,
                                              float* __restrict__ qW,
                                              float* __restrict__ qb) {
    const int t = threadIdx.x;
    if (blockIdx.x < 2048) {
        int idx = blockIdx.x * 256 + t;
        int k = idx >> 8, n = idx & 255;
        wtb[n * TOKD + k] = f2bf(W[idx]);
        return;
    }
    __shared__ float qpart[8][32];
    __shared__ float qhl[32];
    const int h = blockIdx.x - 2048;
    const int col = h * 32 + (t & 31), sl = t >> 5;
    float s = 0.f;
    #pragma unroll
    for (int e = 0; e < 32; ++e) s += pq[sl * 32 + e] * Wq[(sl * 32 + e) * D_ + col];
    qpart[sl][t & 31] = s;
    __syncthreads();
    if (t < 32) {
        float u = bqv[h * 32 + t];
        #pragma unroll
        for (int s8 = 0; s8 < 8; ++s8) u += qpart[s8][t];
        qhl[t] = u;
    }
    __syncthreads();
    float u = 0.f;
    #pragma unroll
    for (int dd = 0; dd < 32; ++dd) u += qhl[dd] * Wk[t * D_ + h * 32 + dd];
    qW[h * D_ + t] = u;
    if (t == 0) {
        float z = 0.f;
        for (int dd = 0; dd < 32; ++dd) z += qhl[dd] * bkv[h * 32 + dd];
        qb[h] = z;
    }
}

// ---------- GEMM1 + bias + LN fused. A bf16 reg-staged, B gload_lds, counted vmcnt ----------
__global__ __launch_bounds__(512, 2) void k_gemm1(const float* __restrict__ A,
                                                  const unsigned short* __restrict__ Bt,
                                                  const float* __restrict__ btok,
                                                  const float* __restrict__ g,
                                                  const float* __restrict__ bt,
                                                  unsigned short* __restrict__ tp) {
    // A bufs (bf16): [0,16K),[16K,32K); B bufs: [32K,64K),[64K,96K). Epilogue reuses [0,66.6K).
    __shared__ __align__(16) char smem[98304];
    const int t = threadIdx.x;
    const int bm = blockIdx.x;
    const int lane = t & 63, w = t >> 6;
    const int wm = w >> 2, wn = w & 3;       // 2x4 waves, wave tile 64x64
    const int lr = lane >> 4, lc = lane & 15;

    // A reg-staging: thread owns row t>>2, 16 f32 at col (t&3)*16
    const int arow = t >> 2;
    const int acb = (t & 3) * 32;            // byte col base after cast
    const float* agp = A + (size_t)(bm * 128 + arow) * TOKD + (t & 3) * 16;
    const int aw0 = arow * 128 + (acb ^ ((arow & 7) << 4));
    const int aw1 = arow * 128 + ((acb + 16) ^ ((arow & 7) << 4));
    // B gload (pre-swizzled global source, linear LDS dst)
    const unsigned short* bg = Bt + (size_t)(t >> 3) * TOKD
                        + (((((t & 7) << 4)) ^ (((t >> 3) & 7) << 4)) >> 1);
    char* bldsw = smem + 32768 + (t >> 6) * 1024;   // wave-uniform base

    f32x4 acc[4][4] = {};
    const int NT = TOKD / 64;   // 32
    float4 a0, a1, a2, a3;

    // prologue: tile0 -> buf0
    a0 = *(const float4*)(agp);     a1 = *(const float4*)(agp + 4);
    a2 = *(const float4*)(agp + 8); a3 = *(const float4*)(agp + 12);
    #pragma unroll
    for (int c = 0; c < 4; ++c) gload16(bg + (size_t)c * 64 * TOKD, bldsw + c * 8192);
    {
        uint4 w0, w1;
        w0.x = pkbf(a0.x, a0.y); w0.y = pkbf(a0.z, a0.w);
        w0.z = pkbf(a1.x, a1.y); w0.w = pkbf(a1.z, a1.w);
        w1.x = pkbf(a2.x, a2.y); w1.y = pkbf(a2.z, a2.w);
        w1.z = pkbf(a3.x, a3.y); w1.w = pkbf(a3.z, a3.w);
        *(uint4*)(smem + aw0) = w0; *(uint4*)(smem + aw1) = w1;
    }
    a0 = *(const float4*)(agp + 64);  a1 = *(const float4*)(agp + 68);   // tile1 -> regs
    a2 = *(const float4*)(agp + 72);  a3 = *(const float4*)(agp + 76);
    asm volatile("s_waitcnt vmcnt(4) lgkmcnt(0)" ::: "memory");   // B0 done; A1 in flight
    __builtin_amdgcn_s_barrier();

    int cur = 0;
    for (int kt = 0; kt < NT; ++kt) {
        const int nxt = cur ^ 1;
        if (kt + 1 < NT) {   // issue B(kt+1) -> buf nxt (in flight across compute)
            const unsigned short* bn = bg + (size_t)(kt + 1) * 64;
            #pragma unroll
            for (int c = 0; c < 4; ++c)
                gload16(bn + (size_t)c * 64 * TOKD, bldsw + nxt * 32768 + c * 8192);
        }
        const char* Ab = smem + cur * 16384;
        const char* Bb = smem + 32768 + cur * 32768;
        #pragma unroll
        for (int kk = 0; kk < 2; ++kk) {
            short8 afr[4], bfr[4];
            #pragma unroll
            for (int mi = 0; mi < 4; ++mi) {
                int row = wm * 64 + mi * 16 + lc;
                afr[mi] = *(const short8*)(Ab + row * 128 + ((kk * 64 + lr * 16) ^ ((row & 7) << 4)));
            }
            #pragma unroll
            for (int ni = 0; ni < 4; ++ni) {
                int n = wn * 64 + ni * 16 + lc;
                bfr[ni] = *(const short8*)(Bb + n * 128 + ((kk * 64 + lr * 16) ^ ((n & 7) << 4)));
            }
            __builtin_amdgcn_s_setprio(1);
            #pragma unroll
            for (int mi = 0; mi < 4; ++mi)
                #pragma unroll
                for (int ni = 0; ni < 4; ++ni)
                    acc[mi][ni] = __builtin_amdgcn_mfma_f32_16x16x32_bf16(afr[mi], bfr[ni], acc[mi][ni], 0, 0, 0);
            __builtin_amdgcn_s_setprio(0);
        }
        if (kt + 1 < NT) {
            char* Anw = smem + nxt * 16384;   // write A(kt+1) (compiler waits its regs)
            uint4 w0, w1;
            w0.x = pkbf(a0.x, a0.y); w0.y = pkbf(a0.z, a0.w);
            w0.z = pkbf(a1.x, a1.y); w0.w = pkbf(a1.z, a1.w);
            w1.x = pkbf(a2.x, a2.y); w1.y = pkbf(a2.z, a2.w);
            w1.z = pkbf(a3.x, a3.y); w1.w = pkbf(a3.z, a3.w);
            *(uint4*)(Anw + aw0) = w0; *(uint4*)(Anw + aw1) = w1;
            if (kt + 2 < NT) {   // A(kt+2) -> regs, left in flight
                const float* ap = agp + (size_t)(kt + 2) * 64;
                a0 = *(const float4*)(ap);     a1 = *(const float4*)(ap + 4);
                a2 = *(const float4*)(ap + 8); a3 = *(const float4*)(ap + 12);
                asm volatile("s_waitcnt vmcnt(4) lgkmcnt(0)" ::: "memory");  // B(kt+1) done
            } else {
                asm volatile("s_waitcnt vmcnt(0) lgkmcnt(0)" ::: "memory");
            }
            __builtin_amdgcn_s_barrier();
            cur = nxt;
        }
    }
    __syncthreads();

    // ---- fused epilogue: bias + LN + bf16 store
    float* ep = (float*)smem;
    const int col0 = lane * 4;
    float4 b4 = *(const float4*)(btok + col0);
    float4 g4 = *(const float4*)(g + col0);
    float4 t4 = *(const float4*)(bt + col0);
    #pragma unroll
    for (int chunk = 0; chunk < 2; ++chunk) {
        if (wm == chunk) {
            #pragma unroll
            for (int mi = 0; mi < 4; ++mi)
                #pragma unroll
                for (int ni = 0; ni < 4; ++ni)
                    #pragma unroll
                    for (int r = 0; r < 4; ++r)
                        ep[(mi * 16 + lr * 4 + r) * 260 + wn * 64 + ni * 16 + lc] = acc[mi][ni][r];
        }
        __syncthreads();
        #pragma unroll
        for (int rr = 0; rr < 8; ++rr) {
            int row = w * 8 + rr;
            float4 x4 = *(const float4*)(ep + row * 260 + col0);
            float x0 = x4.x + b4.x, x1 = x4.y + b4.y, x2 = x4.z + b4.z, x3 = x4.w + b4.w;
            float s = x0 + x1 + x2 + x3;
            float q = x0*x0 + x1*x1 + x2*x2 + x3*x3;
            #pragma unroll
            for (int m = 1; m < 64; m <<= 1) { s += __shfl_xor(s, m); q += __shfl_xor(q, m); }
            float mean = s * (1.f/256.f);
            float var = q * (1.f/256.f) - mean * mean;
            float rs = rsqrtf(var + 1e-5f);
            ushort4 o;
            o.x = f2bf((x0-mean)*rs*g4.x + t4.x);
            o.y = f2bf((x1-mean)*rs*g4.y + t4.y);
            o.z = f2bf((x2-mean)*rs*g4.z + t4.z);
            o.w = f2bf((x3-mean)*rs*g4.w + t4.w);
            *(ushort4*)(tp + (size_t)(bm * 128 + chunk * 64 + row) * D_ + col0) = o;
        }
        __syncthreads();
    }
}

// ---------- top-128 per (b,o) row (exact jax tie-break) + row sum ----------
__global__ __launch_bounds__(256) void k_topk(const float* __restrict__ act,
                                              int* __restrict__ oidx,
                                              float* __restrict__ asum) {
    __shared__ float redf[4];
    __shared__ int redi[4];
    __shared__ int cnts[2];
    __shared__ int eql[4096];
    const int t = threadIdx.x, lane = t & 63, wid = t >> 6;
    const int blk = blockIdx.x;
    const float* rp = act + (size_t)blk * N_;
    unsigned v[16];
    float fs = 0.f;
    #pragma unroll
    for (int i = 0; i < 16; ++i) {
        float f = rp[t + i * 256];
        v[i] = __float_as_uint(f);
        fs += f;
    }
    if (t == 0) { cnts[0] = 0; cnts[1] = 0; }
    #pragma unroll
    for (int m = 1; m < 64; m <<= 1) fs += __shfl_xor(fs, m);
    if (!lane) redf[wid] = fs;
    __syncthreads();
    if (t == 0) asum[blk] = fmaxf(redf[0] + redf[1] + redf[2] + redf[3], 1e-8f);

    unsigned thr = 0u;
    for (int bit = 31; bit >= 0; --bit) {
        unsigned cand = thr | (1u << bit);
        int c = 0;
        #pragma unroll
        for (int i = 0; i < 16; ++i) c += (v[i] >= cand) ? 1 : 0;
        #pragma unroll
        for (int m = 1; m < 64; m <<= 1) c += __shfl_xor(c, m);
        __syncthreads();
        if (!lane) redi[wid] = c;
        __syncthreads();
        int tot = redi[0] + redi[1] + redi[2] + redi[3];
        if (tot >= K_) thr = cand;
    }
    #pragma unroll
    for (int i = 0; i < 16; ++i) {
        unsigned x = v[i];
        if (x > thr) {
            int p = atomicAdd(&cnts[0], 1);
            oidx[blk * K_ + p] = t + i * 256;
        } else if (x == thr) {
            int p = atomicAdd(&cnts[1], 1);
            eql[p] = t + i * 256;
        }
    }
    __syncthreads();
    const int gc = cnts[0], E = cnts[1], m = K_ - gc;
    int last = -1;
    for (int slot = 0; slot < m; ++slot) {
        int best = 0x7FFFFFFF;
        for (int i = t; i < E; i += 256) {
            int e = eql[i];
            if (e > last && e < best) best = e;
        }
        #pragma unroll
        for (int mm = 1; mm < 64; mm <<= 1) best = min(best, __shfl_xor(best, mm));
        __syncthreads();
        if (!lane) redi[wid] = best;
        __syncthreads();
        best = min(min(redi[0], redi[1]), min(redi[2], redi[3]));
        if (t == 0) oidx[blk * K_ + gc + slot] = best;
        last = best;
    }
}

// ---------- weighted-average partials (grid z-split x5 for occupancy) ----------
__global__ __launch_bounds__(256) void k_wavg(const float* __restrict__ act,
                                              const unsigned short* __restrict__ tp,
                                              float* __restrict__ partial) {
    const int kc = blockIdx.x;   // 32 chunks of 128 n
    const int b = blockIdx.y;    // 8
    const int d = threadIdx.x;
    const unsigned short* tpb = tp + ((size_t)b * N_ + kc * 128) * D_ + d;
    const float* actb = act + (size_t)b * O_ * N_ + kc * 128;
    float* pout = partial + ((size_t)(b * 32 + kc) * O_) * D_ + d;
    for (int oci = 0; oci < 2; ++oci) {
        const int oc = blockIdx.z * 2 + oci;
        float acc[10] = {};
        for (int q = 0; q < 32; ++q) {
            float t0 = bf2f(tpb[(q * 4 + 0) * D_]);
            float t1 = bf2f(tpb[(q * 4 + 1) * D_]);
            float t2 = bf2f(tpb[(q * 4 + 2) * D_]);
            float t3 = bf2f(tpb[(q * 4 + 3) * D_]);
            #pragma unroll
            for (int oj = 0; oj < 10; ++oj) {
                float4 a4 = *(const float4*)(actb + (size_t)(oc * 10 + oj) * N_ + q * 4);
                acc[oj] += a4.x * t0 + a4.y * t1 + a4.z * t2 + a4.w * t3;
            }
        }
        #pragma unroll
        for (int oj = 0; oj < 10; ++oj)
            pout[(size_t)(oc * 10 + oj) * D_] = acc[oj];
    }
}

// ---------- gather + attention + Wv/Wo + LN + combine + final LN ----------
DEVI int swz(int j, int chunk) { return j * 512 + ((chunk ^ (j & 31)) << 4); }

__global__ __launch_bounds__(256) void k_attn(
    const unsigned short* __restrict__ tp, const int* __restrict__ oidx,
    const float* __restrict__ qW, const float* __restrict__ qbv,
    const float* __restrict__ Wv, const float* __restrict__ bv,
    const float* __restrict__ Wo, const float* __restrict__ bo,
    const float* __restrict__ g_pn, const float* __restrict__ bt_pn,
    const float* __restrict__ g_on, const float* __restrict__ bt_on,
    const float* __restrict__ partial, const float* __restrict__ asum,
    float* __restrict__ outp)
{
    __shared__ uint4 tgU[4096];      // 128 rows x 512B, chunk-XOR swizzle
    __shared__ float sc[H_ * K_];    // [h][j]; raw then normalized in place
    __shared__ float ul[H_ * D_];
    __shared__ float pool_lds[D_];
    __shared__ float redf[8];
    __shared__ int idxl[K_];
    char* tg = (char*)tgU;

    const int t = threadIdx.x, lane = t & 63, wid = t >> 6;
    const int blk = blockIdx.x;
    const int b = blk / O_;
    const int o = blk - b * O_;

    if (t < K_) idxl[t] = oidx[blk * K_ + t];
    __syncthreads();

    #pragma unroll
    for (int it = 0; it < 16; ++it) {      // gather top-128 token rows (bf16)
        int c = t + it * 256;
        int j = c >> 5, ch = c & 31;
        uint4 v = *(const uint4*)(tp + ((size_t)(b * N_ + idxl[j])) * D_ + ch * 8);
        *(uint4*)(tg + swz(j, ch)) = v;
    }
    __syncthreads();

    {   // QK: thread = (j = t&127, h-quad = t>>7): 4 scores per row pass
        const int j = t & 127, hq = t >> 7;
        const float* q0 = qW + hq * 4 * D_;
        float s0 = 0.f, s1 = 0.f, s2 = 0.f, s3 = 0.f;
        #pragma unroll 4
        for (int e8 = 0; e8 < 32; ++e8) {
            uint4 tv = *(const uint4*)(tg + swz(j, e8));
            float f0 = bf2f(tv.x & 0xffffu), f1 = bf2f(tv.x >> 16);
            float f2 = bf2f(tv.y & 0xffffu), f3 = bf2f(tv.y >> 16);
            float f4 = bf2f(tv.z & 0xffffu), f5 = bf2f(tv.z >> 16);
            float f6 = bf2f(tv.w & 0xffffu), f7 = bf2f(tv.w >> 16);
            const float* qa = q0 + e8 * 8;
            const float* qbp = qa + D_;
            const float* qc = qa + 2 * D_;
            const float* qd = qa + 3 * D_;
            s0 += f0*qa[0]+f1*qa[1]+f2*qa[2]+f3*qa[3]+f4*qa[4]+f5*qa[5]+f6*qa[6]+f7*qa[7];
            s1 += f0*qbp[0]+f1*qbp[1]+f2*qbp[2]+f3*qbp[3]+f4*qbp[4]+f5*qbp[5]+f6*qbp[6]+f7*qbp[7];
            s2 += f0*qc[0]+f1*qc[1]+f2*qc[2]+f3*qc[3]+f4*qc[4]+f5*qc[5]+f6*qc[6]+f7*qc[7];
            s3 += f0*qd[0]+f1*qd[1]+f2*qd[2]+f3*qd[3]+f4*qd[4]+f5*qd[5]+f6*qd[6]+f7*qd[7];
        }
        const float sca = 0.1767766952966369f;
        sc[(hq * 4 + 0) * K_ + j] = (s0 + qbv[hq * 4 + 0]) * sca;
        sc[(hq * 4 + 1) * K_ + j] = (s1 + qbv[hq * 4 + 1]) * sca;
        sc[(hq * 4 + 2) * K_ + j] = (s2 + qbv[hq * 4 + 2]) * sca;
        sc[(hq * 4 + 3) * K_ + j] = (s3 + qbv[hq * 4 + 3]) * sca;
    }
    __syncthreads();

    #pragma unroll
    for (int hh = 0; hh < 2; ++hh) {       // softmax per head, normalize in place
        int h = wid * 2 + hh;
        float v0 = sc[h * K_ + lane], v1 = sc[h * K_ + 64 + lane];
        float mx = fmaxf(v0, v1);
        #pragma unroll
        for (int m = 1; m < 64; m <<= 1) mx = fmaxf(mx, __shfl_xor(mx, m));
        float e0 = __expf(v0 - mx), e1 = __expf(v1 - mx);
        float ss = e0 + e1;
        #pragma unroll
        for (int m = 1; m < 64; m <<= 1) ss += __shfl_xor(ss, m);
        float inv = 1.0f / ss;
        sc[h * K_ + lane] = e0 * inv;
        sc[h * K_ + 64 + lane] = e1 * inv;
    }
    __syncthreads();

    {   // PV: thread = (h = t>>5, eg = t&31 -> 8 e's); b128 token reads + broadcast weights
        const int h = t >> 5, eg = t & 31;
        float a8[8] = {};
        #pragma unroll 2
        for (int jb = 0; jb < 32; ++jb) {
            f32x4 p4 = *(const f32x4*)(sc + h * K_ + jb * 4);
            #pragma unroll
            for (int ji = 0; ji < 4; ++ji) {
                int j = jb * 4 + ji;
                uint4 tv = *(const uint4*)(tg + swz(j, eg));
                float pw = p4[ji];
                a8[0] += pw * bf2f(tv.x & 0xffffu); a8[1] += pw * bf2f(tv.x >> 16);
                a8[2] += pw * bf2f(tv.y & 0xffffu); a8[3] += pw * bf2f(tv.y >> 16);
                a8[4] += pw * bf2f(tv.z & 0xffffu); a8[5] += pw * bf2f(tv.z >> 16);
                a8[6] += pw * bf2f(tv.w & 0xffffu); a8[7] += pw * bf2f(tv.w >> 16);
            }
        }
        #pragma unroll
        for (int i = 0; i < 8; ++i) ul[h * D_ + eg * 8 + i] = a8[i];
    }
    __syncthreads();

    {   // pooled[c] = u[h,:] @ Wv[:, c] + bv  (c = t, h = c>>5)
        int h = t >> 5;
        const float* up = ul + h * D_;
        float p = bv[t];
        for (int e = 0; e < D_; ++e) p += up[e] * Wv[e * D_ + t];
        pool_lds[t] = p;
    }
    __syncthreads();
    float po = bo[t];
    for (int e = 0; e < D_; ++e) po += pool_lds[e] * Wo[e * D_ + t];

    // LN (g_pn)
    float s1 = po, q1 = po * po;
    #pragma unroll
    for (int m = 1; m < 64; m <<= 1) { s1 += __shfl_xor(s1, m); q1 += __shfl_xor(q1, m); }
    if (!lane) { redf[wid] = s1; redf[4 + wid] = q1; }
    __syncthreads();
    s1 = redf[0] + redf[1] + redf[2] + redf[3];
    q1 = redf[4] + redf[5] + redf[6] + redf[7];
    float mean = s1 * (1.f/256.f);
    float var = q1 * (1.f/256.f) - mean * mean;
    float rs = rsqrtf(var + 1e-5f);
    float pl = (po - mean) * rs * g_pn[t] + bt_pn[t];
    __syncthreads();

    // combine with weighted average (sum 32 partials), final LN (g_on)
    float wa = 0.f;
    const float* pp = partial + ((size_t)(b * 32) * O_ + o) * D_ + t;
    #pragma unroll 8
    for (int kc = 0; kc < 32; ++kc) wa += pp[(size_t)kc * O_ * D_];
    float x = wa / asum[blk] + pl;
    float s2 = x, q2 = x * x;
    #pragma unroll
    for (int m = 1; m < 64; m <<= 1) { s2 += __shfl_xor(s2, m); q2 += __shfl_xor(q2, m); }
    if (!lane) { redf[wid] = s2; redf[4 + wid] = q2; }
    __syncthreads();
    s2 = redf[0] + redf[1] + redf[2] + redf[3];
    q2 = redf[4] + redf[5] + redf[6] + redf[7];
    float mean2 = s2 * (1.f/256.f);
    float var2 = q2 * (1.f/256.f) - mean2 * mean2;
    float rs2 = rsqrtf(var2 + 1e-5f);
    outp[(size_t)blk * D_ + t] = (x - mean2) * rs2 * g_on[t] + bt_on[t];
}

extern "C" void kernel_launch(void* const* d_in, const int* in_sizes, int n_in,
                              void* d_out, int out_size, void* d_ws, size_t ws_size,
                              hipStream_t stream) {
    const float* act    = (const float*)d_in[0];
    const float* tokens = (const float*)d_in[1];
    const float* W_tok  = (const float*)d_in[2];
    const float* b_tok  = (const float*)d_in[3];
    const float* g_tn   = (const float*)d_in[4];
    const float* bt_tn  = (const float*)d_in[5];
    const float* pq     = (const float*)d_in[6];
    const float* Wq     = (const float*)d_in[7];
    const float* bq     = (const float*)d_in[8];
    const float* Wk     = (const float*)d_in[9];
    const float* bk     = (const float*)d_in[10];
    const float* Wv     = (const float*)d_in[11];
    const float* bv     = (const float*)d_in[12];
    const float* Wo     = (const float*)d_in[13];
    const float* bo     = (const float*)d_in[14];
    const float* g_pn   = (const float*)d_in[15];
    const float* bt_pn  = (const float*)d_in[16];
    const float* g_on   = (const float*)d_in[17];
    const float* bt_on  = (const float*)d_in[18];

    char* ws = (char*)d_ws;
    unsigned short* wtb   = (unsigned short*)ws;                 // 1 MB
    unsigned short* tp    = (unsigned short*)(ws + 1048576);     // 16 MB
    int*   tidx = (int*)(ws + 17825792);                         // 409600
    float* asum = (float*)(ws + 18235392);                       // 3200
    float* part = (float*)(ws + 18238592);                       // 26.2 MB
    float* qW   = (float*)(ws + 44452992);                       // 8 KB
    float* qb   = (float*)(ws + 44461184);                       // 32 B

    k_prep<<<2056, 256, 0, stream>>>(W_tok, wtb, pq, Wq, bq, Wk, bk, qW, qb);
    k_gemm1<<<M_ / 128, 512, 0, stream>>>(tokens, wtb, b_tok, g_tn, bt_tn, tp);
    k_topk<<<B_ * O_, 256, 0, stream>>>(act, tidx, asum);
    k_wavg<<<dim3(32, 8, 5), 256, 0, stream>>>(act, tp, part);
    k_attn<<<B_ * O_, 256, 0, stream>>>(tp, tidx, qW, qb, Wv, bv, Wo, bo,
                                        g_pn, bt_pn, g_on, bt_on, part, asum,
                                        (float*)d_out);
}